// Round 1
// baseline (133.752 us; speedup 1.0000x reference)
//
#include <hip/hip_runtime.h>
#include <hip/hip_fp16.h>

// Raymarcher: R=16384 rays, 64 steps, K=32 prims, template (32,4,16,16,16) f32.
// Round 11: lane = STEP (64 lanes = 64 steps, 1 ray/wave). Since salpha >= 0,
// the alpha recursion clip(a+inc,0,1) == min(prefix,1): compute all per-step
// prim-sums independently, then ONE 64-lane prefix scan -> contrib per step,
// ONE rgb reduce per wave. Loop over prims gated by an exact slab (ray/box)
// test computed once per wave (prim-per-lane + ballot bitmask), so trilinear
// runs once per *intersected* prim. Eliminates the per-iteration 6-shuffle
// reduce + serial alpha chain of r10. fp16 channel-last template kept from r9.

namespace {

constexpr float kDT  = 1.0f / 64.0f;
constexpr int   kVox = 32 * 4096;   // (k,z,y,x) voxel count

struct H4 { __half2 lo, hi; };                                   // one voxel, 8 B
struct __attribute__((aligned(8))) H4x2 { __half2 l0, h0, l1, h1; }; // voxels (x, x+1), 16 B

// ---- pre-pass: (k,c,z,y,x) f32 -> (k,z,y,x,c) fp16 ----
__global__ __launch_bounds__(256) void transpose_tmpl_h(
    const float* __restrict__ tmpl, H4* __restrict__ wsH)
{
    const int idx = blockIdx.x * 256 + threadIdx.x;     // < 131072
    const int k   = idx >> 12;
    const int rem = idx & 4095;
    const float* src = tmpl + k * 16384 + rem;
    H4 v;
    v.lo = __floats2half2_rn(src[0],    src[4096]);
    v.hi = __floats2half2_rn(src[8192], src[12288]);
    wsH[idx] = v;
}

__device__ __forceinline__ __half2 lerp2(__half2 a, __half2 b, __half2 f) {
    return __hfma2(f, __hsub2(b, a), a);
}

__device__ __forceinline__ float bcast_lane(float v, int srcLane) {
    return __uint_as_float(__builtin_amdgcn_readlane(__float_as_uint(v), srcLane));
}

__global__ __launch_bounds__(256) void raymarch11(
    const float* __restrict__ raypos,
    const float* __restrict__ raydir,
    const float* __restrict__ tminmax,
    const float* __restrict__ primpos,
    const float* __restrict__ primrot,
    const float* __restrict__ primscale,
    const H4* __restrict__ wsH,
    float* __restrict__ out,
    int R)
{
    const int lane = threadIdx.x & 63;
    const int wid  = threadIdx.x >> 6;        // wave 0..3
    const int ray  = blockIdx.x * 4 + wid;    // one ray per wave
    const int k    = lane & 31;               // prim tested by this lane (slab pass)

    const float rpx = raypos[ray * 3 + 0];
    const float rpy = raypos[ray * 3 + 1];
    const float rpz = raypos[ray * 3 + 2];
    const float rdx = raydir[ray * 3 + 0];
    const float rdy = raydir[ray * 3 + 1];
    const float rdz = raydir[ray * 3 + 2];
    const float tmin = tminmax[ray * 2 + 0];
    const float tmax = tminmax[ray * 2 + 1];

    // Per-prim affine y_i(t) = A_i + D_i*t (verified r1-r10 math).
    // Lane l computes prim l&31 (upper half duplicates lower half).
    float A0, A1, A2, D0, D1, D2;
    {
        const float ox = rpx - primpos[k * 3 + 0];
        const float oy = rpy - primpos[k * 3 + 1];
        const float oz = rpz - primpos[k * 3 + 2];
        const float s0 = primscale[k * 3 + 0];
        const float s1 = primscale[k * 3 + 1];
        const float s2 = primscale[k * 3 + 2];
        const float* rk = primrot + k * 9;
        A0 = (rk[0] * ox + rk[1] * oy + rk[2] * oz) * s0;
        D0 = (rk[0] * rdx + rk[1] * rdy + rk[2] * rdz) * s0;
        A1 = (rk[3] * ox + rk[4] * oy + rk[5] * oz) * s1;
        D1 = (rk[3] * rdx + rk[4] * rdy + rk[5] * rdz) * s1;
        A2 = (rk[6] * ox + rk[7] * oy + rk[8] * oz) * s2;
        D2 = (rk[6] * rdx + rk[7] * rdy + rk[8] * rdz) * s2;
    }

    // Exact slab test for prim k vs segment [tmin, min(tmax, tmin+63*DT)],
    // padded by 2*DT so fp/rcp boundary error can only ADD prims (the
    // per-lane |y|<=1 test below remains the authority).
    unsigned mask;
    {
        const float i0 = 1.0f / D0, i1 = 1.0f / D1, i2 = 1.0f / D2;
        const float a0 = (-1.0f - A0) * i0, b0 = (1.0f - A0) * i0;
        const float a1 = (-1.0f - A1) * i1, b1 = (1.0f - A1) * i1;
        const float a2 = (-1.0f - A2) * i2, b2 = (1.0f - A2) * i2;
        const float tEnd = fminf(tmax, fmaf(63.0f, kDT, tmin));
        const float lo = fmaxf(fmaxf(fminf(a0, b0), fminf(a1, b1)),
                               fmaxf(fminf(a2, b2), tmin));
        const float hi = fminf(fminf(fmaxf(a0, b0), fmaxf(a1, b1)),
                               fminf(fmaxf(a2, b2), tEnd));
        const bool active = lo <= hi + 2.0f * kDT;
        mask = (unsigned)(__ballot(active) & 0xffffffffull);   // low-half bits
    }

    const float t_l = fmaf((float)lane, kDT, tmin);   // this lane's step time

    // Per-step (per-lane) sums over prims.
    float s0 = 0.f, s1 = 0.f, s2 = 0.f, s3 = 0.f;

    while (mask) {
        const int kk = __builtin_ctz(mask);
        mask &= mask - 1;

        const float bA0 = bcast_lane(A0, kk);
        const float bA1 = bcast_lane(A1, kk);
        const float bA2 = bcast_lane(A2, kk);
        const float bD0 = bcast_lane(D0, kk);
        const float bD1 = bcast_lane(D1, kk);
        const float bD2 = bcast_lane(D2, kk);

        const float y0 = fmaf(bD0, t_l, bA0);
        const float y1 = fmaf(bD1, t_l, bA1);
        const float y2 = fmaf(bD2, t_l, bA2);
        const bool inside = fabsf(y0) <= 1.0f && fabsf(y1) <= 1.0f
                         && fabsf(y2) <= 1.0f;
        if (inside) {
            const float gz = fmaf(y0, 7.5f, 7.5f);   // in [0,15], single-rounded
            const float gy = fmaf(y1, 7.5f, 7.5f);
            const float gx = fmaf(y2, 7.5f, 7.5f);
            const int iz = min((int)gz, 14);          // trunc == floor, g>=0
            const int iy = min((int)gy, 14);
            const int ix = min((int)gx, 14);
            const float fz = fminf(gz - (float)iz, 1.0f);
            const float fy = fminf(gy - (float)iy, 1.0f);
            const float fx = fminf(gx - (float)ix, 1.0f);

            const H4* tp = wsH + (kk << 12) + (iz * 256 + iy * 16 + ix);
            const H4x2 p00 = *(const H4x2*)(tp + 0);    // (z0,y0,x0..x1)
            const H4x2 p01 = *(const H4x2*)(tp + 16);   // (z0,y1,x0..x1)
            const H4x2 p10 = *(const H4x2*)(tp + 256);  // (z1,y0,x0..x1)
            const H4x2 p11 = *(const H4x2*)(tp + 272);  // (z1,y1,x0..x1)

            const __half2 hz = __float2half2_rn(fz);
            const __half2 hy = __float2half2_rn(fy);
            const __half2 hx = __float2half2_rn(fx);

            // factorized trilinear: z -> y -> x on (r,g)/(b,a) packed pairs
            const __half2 q0l0 = lerp2(p00.l0, p10.l0, hz);
            const __half2 q0h0 = lerp2(p00.h0, p10.h0, hz);
            const __half2 q0l1 = lerp2(p00.l1, p10.l1, hz);
            const __half2 q0h1 = lerp2(p00.h1, p10.h1, hz);
            const __half2 q1l0 = lerp2(p01.l0, p11.l0, hz);
            const __half2 q1h0 = lerp2(p01.h0, p11.h0, hz);
            const __half2 q1l1 = lerp2(p01.l1, p11.l1, hz);
            const __half2 q1h1 = lerp2(p01.h1, p11.h1, hz);

            const __half2 ul0 = lerp2(q0l0, q1l0, hy);
            const __half2 uh0 = lerp2(q0h0, q1h0, hy);
            const __half2 ul1 = lerp2(q0l1, q1l1, hy);
            const __half2 uh1 = lerp2(q0h1, q1h1, hy);

            const __half2 vl = lerp2(ul0, ul1, hx);
            const __half2 vh = lerp2(uh0, uh1, hx);

            const float2 fLo = __half22float2(vl);
            const float2 fHi = __half22float2(vh);
            s0 += fLo.x; s1 += fLo.y; s2 += fHi.x; s3 += fHi.y;
        }
    }

    // Alpha via prefix scan: inc >= 0 (softplus density, convex weights)
    // => clip(a+inc,0,1) == min(prefix,1) (same identity r10 relied on).
    const bool valid = t_l < tmax;
    const float inc = valid ? s3 * kDT : 0.0f;
    float p = inc;
    #pragma unroll
    for (int d = 1; d < 64; d <<= 1) {
        const float n = __shfl_up(p, d, 64);
        if (lane >= d) p += n;
    }
    float ex = __shfl_up(p, 1, 64);           // exclusive prefix (exact)
    if (lane == 0) ex = 0.0f;
    const float contrib = fminf(p, 1.0f) - fminf(ex, 1.0f);

    float r0 = s0 * contrib;
    float r1 = s1 * contrib;
    float r2 = s2 * contrib;
    #pragma unroll
    for (int m = 1; m < 64; m <<= 1) {
        r0 += __shfl_xor(r0, m);
        r1 += __shfl_xor(r1, m);
        r2 += __shfl_xor(r2, m);
    }
    const float alpha = fminf(__shfl(p, 63, 64), 1.0f);

    if (lane == 0) {
        out[0 * R + ray] = r0;
        out[1 * R + ray] = r1;
        out[2 * R + ray] = r2;
        out[3 * R + ray] = alpha;
        out[4 * R + ray] = r0;
        out[5 * R + ray] = r1;
        out[6 * R + ray] = r2;
        out[7 * R + ray] = alpha;
    }
}

// ---- fallback (r6-style, original f32 template) for tiny ws ----
__global__ __launch_bounds__(256) void raymarch_fb(
    const float* __restrict__ raypos, const float* __restrict__ raydir,
    const float* __restrict__ tminmax, const float* __restrict__ primpos,
    const float* __restrict__ primrot, const float* __restrict__ primscale,
    const float* __restrict__ tmpl, float* __restrict__ out, int R)
{
    const int lane = threadIdx.x & 63;
    const int wid  = threadIdx.x >> 6;
    const int k    = lane & 31;
    const int half = lane >> 5;
    const int ray  = blockIdx.x * 8 + wid * 2 + half;

    const float rpx = raypos[ray*3+0], rpy = raypos[ray*3+1], rpz = raypos[ray*3+2];
    const float rdx = raydir[ray*3+0], rdy = raydir[ray*3+1], rdz = raydir[ray*3+2];
    const float tmin = tminmax[ray*2+0], tmax = tminmax[ray*2+1];

    float A0,A1,A2,D0,D1,D2;
    {
        const float ox = rpx - primpos[k*3+0], oy = rpy - primpos[k*3+1], oz = rpz - primpos[k*3+2];
        const float s0 = primscale[k*3+0], s1 = primscale[k*3+1], s2 = primscale[k*3+2];
        const float* rk = primrot + k*9;
        A0 = (rk[0]*ox+rk[1]*oy+rk[2]*oz)*s0; D0 = (rk[0]*rdx+rk[1]*rdy+rk[2]*rdz)*s0;
        A1 = (rk[3]*ox+rk[4]*oy+rk[5]*oz)*s1; D1 = (rk[3]*rdx+rk[4]*rdy+rk[5]*rdz)*s1;
        A2 = (rk[6]*ox+rk[7]*oy+rk[8]*oz)*s2; D2 = (rk[6]*rdx+rk[7]*rdy+rk[8]*rdz)*s2;
    }
    float alpha = 0.f, r0 = 0.f, r1 = 0.f, r2 = 0.f;
    for (int i = 0; i < 64; ++i) {
        const float t = fmaf((float)i, kDT, tmin);
        const bool live = (t < tmax) && (alpha < 1.0f);
        if (__ballot(live) == 0ull) break;
        const float y0 = fmaf(D0,t,A0), y1 = fmaf(D1,t,A1), y2 = fmaf(D2,t,A2);
        const bool inside = live && fabsf(y0)<=1.f && fabsf(y1)<=1.f && fabsf(y2)<=1.f;
        if (__ballot(inside) == 0ull) continue;
        float s0=0.f,s1=0.f,s2=0.f,s3=0.f;
        if (inside) {
            const float gz=(y0+1.f)*7.5f, gy=(y1+1.f)*7.5f, gx=(y2+1.f)*7.5f;
            const int iz=(int)fminf(floorf(gz),14.f), iy=(int)fminf(floorf(gy),14.f), ix=(int)fminf(floorf(gx),14.f);
            const float fz=fminf(gz-(float)iz,1.f), fy=fminf(gy-(float)iy,1.f), fx=fminf(gx-(float)ix,1.f);
            const float oz_=1.f-fz, oy_=1.f-fy, ox_=1.f-fx;
            const float w000=oz_*oy_*ox_, w001=oz_*oy_*fx, w010=oz_*fy*ox_, w011=oz_*fy*fx;
            const float w100=fz*oy_*ox_, w101=fz*oy_*fx, w110=fz*fy*ox_, w111=fz*fy*fx;
            const float* tp = tmpl + k*16384 + iz*256 + iy*16 + ix;
            float acc[4];
            #pragma unroll
            for (int c = 0; c < 4; ++c) {
                const float* tc = tp + c*4096;
                acc[c] = w000*tc[0]+w001*tc[1]+w010*tc[16]+w011*tc[17]
                       + w100*tc[256]+w101*tc[257]+w110*tc[272]+w111*tc[273];
            }
            s0=acc[0]; s1=acc[1]; s2=acc[2]; s3=acc[3];
        }
        float tot3 = s3;
        #pragma unroll
        for (int m = 1; m < 32; m <<= 1) tot3 += __shfl_xor(tot3, m);
        const float na = fminf(fmaf(tot3, kDT, alpha), 1.0f);
        const float contrib = na - alpha;
        alpha = na;
        r0 = fmaf(s0, contrib, r0); r1 = fmaf(s1, contrib, r1); r2 = fmaf(s2, contrib, r2);
    }
    #pragma unroll
    for (int m = 1; m < 32; m <<= 1) {
        r0 += __shfl_xor(r0, m); r1 += __shfl_xor(r1, m); r2 += __shfl_xor(r2, m);
    }
    if (k == 0) {
        out[0*R+ray]=r0; out[1*R+ray]=r1; out[2*R+ray]=r2; out[3*R+ray]=alpha;
        out[4*R+ray]=r0; out[5*R+ray]=r1; out[6*R+ray]=r2; out[7*R+ray]=alpha;
    }
}

} // namespace

extern "C" void kernel_launch(void* const* d_in, const int* in_sizes, int n_in,
                              void* d_out, int out_size, void* d_ws, size_t ws_size,
                              hipStream_t stream) {
    const float* raypos    = (const float*)d_in[0];
    const float* raydir    = (const float*)d_in[1];
    const float* tminmax   = (const float*)d_in[2];
    const float* primpos   = (const float*)d_in[3];
    const float* primrot   = (const float*)d_in[4];
    const float* primscale = (const float*)d_in[5];
    const float* tmpl      = (const float*)d_in[6];
    float* out = (float*)d_out;

    const int R = in_sizes[0] / 3;   // 16384
    const size_t needH = (size_t)kVox * sizeof(H4);   // 1 MiB

    if (ws_size >= needH) {
        H4* wsH = (H4*)d_ws;
        transpose_tmpl_h<<<dim3(kVox / 256), dim3(256), 0, stream>>>(tmpl, wsH);
        raymarch11<<<dim3(R / 4), dim3(256), 0, stream>>>(
            raypos, raydir, tminmax, primpos, primrot, primscale, wsH, out, R);
    } else {
        raymarch_fb<<<dim3(R / 8), dim3(256), 0, stream>>>(
            raypos, raydir, tminmax, primpos, primrot, primscale, tmpl, out, R);
    }
}

// Round 2
// 90.351 us; speedup vs baseline: 1.4804x; 1.4804x over previous
//
#include <hip/hip_runtime.h>
#include <hip/hip_fp16.h>

// Raymarcher: R=16384 rays, 64 steps, K=32 prims, template (32,4,16,16,16) f32.
// Round 12: back to r10's winning layout (lane=(prim,parity), 2 substeps/iter,
// wave-uniform early break on alpha saturation — the key work-cutter r11 lost),
// plus two latency fixes:
//  (a) DPP butterfly reduce (quad_perm xor1/xor2, row_half_mirror==xor4,
//      row_mirror==xor8 — exact: groups are bit-identical after each stage)
//      + 1 ds_swizzle(xor16) + 1 shfl(xor32). ~70cy vs ~240cy chain.
//  (b) double-buffered software pipeline: iteration j+1's 4x16B template
//      loads are issued (exec-masked) before consuming iteration j, so L2
//      latency hides under the lerp+reduce of the previous step-pair.
// fp16 channel-last template + factorized lerp + 16B x-pair loads from r9/r10.

namespace {

constexpr float kDT  = 1.0f / 64.0f;
constexpr int   kVox = 32 * 4096;   // (k,z,y,x) voxel count

struct H4 { __half2 lo, hi; };                                   // one voxel, 8 B
struct __attribute__((aligned(8))) H4x2 { __half2 l0, h0, l1, h1; }; // voxels (x, x+1), 16 B

// ---- pre-pass: (k,c,z,y,x) f32 -> (k,z,y,x,c) fp16 ----
__global__ __launch_bounds__(256) void transpose_tmpl_h(
    const float* __restrict__ tmpl, H4* __restrict__ wsH)
{
    const int idx = blockIdx.x * 256 + threadIdx.x;     // < 131072
    const int k   = idx >> 12;
    const int rem = idx & 4095;
    const float* src = tmpl + k * 16384 + rem;
    H4 v;
    v.lo = __floats2half2_rn(src[0],    src[4096]);
    v.hi = __floats2half2_rn(src[8192], src[12288]);
    wsH[idx] = v;
}

__device__ __forceinline__ __half2 lerp2(__half2 a, __half2 b, __half2 f) {
    return __hfma2(f, __hsub2(b, a), a);
}

template<int CTRL>
__device__ __forceinline__ float dpp_add(float v) {
    return v + __int_as_float(__builtin_amdgcn_update_dpp(
        0, __float_as_int(v), CTRL, 0xF, 0xF, true));
}

// Sum across each 32-lane half; result in every lane of that half.
// Stages: xor1 (quad_perm), xor2 (quad_perm), xor4 (row_half_mirror — the
// 4-groups are bit-identical after xor1/xor2, so mirror==xor), xor8
// (row_mirror, same argument), xor16 (ds_swizzle BitMode).
__device__ __forceinline__ float half_sum32(float v) {
    v = dpp_add<0xB1>(v);    // quad_perm {1,0,3,2}  == lane^1
    v = dpp_add<0x4E>(v);    // quad_perm {2,3,0,1}  == lane^2
    v = dpp_add<0x141>(v);   // row_half_mirror      == lane^4 (groups uniform)
    v = dpp_add<0x140>(v);   // row_mirror           == lane^8 (groups uniform)
    v += __int_as_float(__builtin_amdgcn_ds_swizzle(__float_as_int(v), 0x401F)); // ^16
    return v;
}

__global__ __launch_bounds__(256) void raymarch12(
    const float* __restrict__ raypos,
    const float* __restrict__ raydir,
    const float* __restrict__ tminmax,
    const float* __restrict__ primpos,
    const float* __restrict__ primrot,
    const float* __restrict__ primscale,
    const H4* __restrict__ wsH,
    float* __restrict__ out,
    int R)
{
    const int lane   = threadIdx.x & 63;
    const int wid    = threadIdx.x >> 6;        // wave 0..3
    const int k      = lane & 31;               // prim owned by this lane
    const int parity = lane >> 5;               // substep parity (0 even, 1 odd)
    const int ray    = blockIdx.x * 4 + wid;    // one ray per wave

    const float rpx = raypos[ray * 3 + 0];
    const float rpy = raypos[ray * 3 + 1];
    const float rpz = raypos[ray * 3 + 2];
    const float rdx = raydir[ray * 3 + 0];
    const float rdy = raydir[ray * 3 + 1];
    const float rdz = raydir[ray * 3 + 2];
    const float tmin = tminmax[ray * 2 + 0];
    const float tmax = tminmax[ray * 2 + 1];

    // Fold prim k into affine y_i(t) = A_i + D_i*t (verified r1-r10 math).
    float A0, A1, A2, D0, D1, D2;
    {
        const float ox = rpx - primpos[k * 3 + 0];
        const float oy = rpy - primpos[k * 3 + 1];
        const float oz = rpz - primpos[k * 3 + 2];
        const float s0 = primscale[k * 3 + 0];
        const float s1 = primscale[k * 3 + 1];
        const float s2 = primscale[k * 3 + 2];
        const float* rk = primrot + k * 9;
        A0 = (rk[0] * ox + rk[1] * oy + rk[2] * oz) * s0;
        D0 = (rk[0] * rdx + rk[1] * rdy + rk[2] * rdz) * s0;
        A1 = (rk[3] * ox + rk[4] * oy + rk[5] * oz) * s1;
        D1 = (rk[3] * rdx + rk[4] * rdy + rk[5] * rdz) * s1;
        A2 = (rk[6] * ox + rk[7] * oy + rk[8] * oz) * s2;
        D2 = (rk[6] * rdx + rk[7] * rdy + rk[8] * rdz) * s2;
    }

    const H4* __restrict__ tbase = wsH + k * 4096;

    float alpha = 0.f;                      // wave-uniform
    float r0 = 0.f, r1 = 0.f, r2 = 0.f;     // per-lane rgb partials

    // ---- double-buffered pipeline state ----
    bool  inA, inB;
    int   adA, adB;
    float fzA, fyA, fxA, fzB, fyB, fxB;
    H4x2  a00, a01, a10, a11, b00, b01, b10, b11;

    // Per-lane coords for substep 2*J+parity. Exact same arithmetic as r10
    // (single-rounded fma forms) so numeric behavior is unchanged.
#define COORDS(J, IN, AD, FZ, FY, FX)                                    \
    {                                                                    \
        const float tl = fmaf((float)(2 * (J) + parity), kDT, tmin);     \
        const float y0 = fmaf(D0, tl, A0);                               \
        const float y1 = fmaf(D1, tl, A1);                               \
        const float y2 = fmaf(D2, tl, A2);                               \
        IN = ((J) < 32) && (tl < tmax) && fabsf(y0) <= 1.0f              \
           && fabsf(y1) <= 1.0f && fabsf(y2) <= 1.0f;                    \
        const float gz = fmaf(y0, 7.5f, 7.5f);                           \
        const float gy = fmaf(y1, 7.5f, 7.5f);                           \
        const float gx = fmaf(y2, 7.5f, 7.5f);                           \
        const int iz = min((int)gz, 14);                                 \
        const int iy = min((int)gy, 14);                                 \
        const int ix = min((int)gx, 14);                                 \
        FZ = fminf(gz - (float)iz, 1.0f);                                \
        FY = fminf(gy - (float)iy, 1.0f);                                \
        FX = fminf(gx - (float)ix, 1.0f);                                \
        AD = iz * 256 + iy * 16 + ix;                                    \
    }

#define PREF(IN, AD, P00, P01, P10, P11)                                 \
    if (IN) {                                                            \
        const H4* tp = tbase + (AD);                                     \
        P00 = *(const H4x2*)(tp + 0);                                    \
        P01 = *(const H4x2*)(tp + 16);                                   \
        P10 = *(const H4x2*)(tp + 256);                                  \
        P11 = *(const H4x2*)(tp + 272);                                  \
    }

#define CONSUME(J, IN, FZ, FY, FX, P00, P01, P10, P11)                   \
    {                                                                    \
        float s0 = 0.f, s1 = 0.f, s2 = 0.f, s3 = 0.f;                    \
        if (IN) {                                                        \
            const __half2 hz = __float2half2_rn(FZ);                     \
            const __half2 hy = __float2half2_rn(FY);                     \
            const __half2 hx = __float2half2_rn(FX);                     \
            const __half2 q0l0 = lerp2(P00.l0, P10.l0, hz);              \
            const __half2 q0h0 = lerp2(P00.h0, P10.h0, hz);              \
            const __half2 q0l1 = lerp2(P00.l1, P10.l1, hz);              \
            const __half2 q0h1 = lerp2(P00.h1, P10.h1, hz);              \
            const __half2 q1l0 = lerp2(P01.l0, P11.l0, hz);              \
            const __half2 q1h0 = lerp2(P01.h0, P11.h0, hz);              \
            const __half2 q1l1 = lerp2(P01.l1, P11.l1, hz);              \
            const __half2 q1h1 = lerp2(P01.h1, P11.h1, hz);              \
            const __half2 ul0 = lerp2(q0l0, q1l0, hy);                   \
            const __half2 uh0 = lerp2(q0h0, q1h0, hy);                   \
            const __half2 ul1 = lerp2(q0l1, q1l1, hy);                   \
            const __half2 uh1 = lerp2(q0h1, q1h1, hy);                   \
            const __half2 vl = lerp2(ul0, ul1, hx);                      \
            const __half2 vh = lerp2(uh0, uh1, hx);                      \
            const float2 fLo = __half22float2(vl);                       \
            const float2 fHi = __half22float2(vh);                       \
            s0 = fLo.x; s1 = fLo.y; s2 = fHi.x; s3 = fHi.y;              \
        }                                                                \
        if (__ballot(IN)) {                                              \
            float tot = half_sum32(s3);                                  \
            const float other = __shfl_xor(tot, 32);                     \
            const float te = parity ? other : tot;    /* even total */   \
            const float to = parity ? tot : other;    /* odd total  */   \
            /* exact 2-substep alpha chain: totals>=0 => clip==min; the  \
               tmax gating is already folded into IN (s*=0 when !IN) */  \
            const float na1 = fminf(fmaf(te, kDT, alpha), 1.0f);         \
            const float c_e = na1 - alpha;                               \
            const float na2 = fminf(fmaf(to, kDT, na1), 1.0f);           \
            const float c_o = na2 - na1;                                 \
            alpha = na2;                                                 \
            const float contrib = parity ? c_o : c_e;                    \
            r0 = fmaf(s0, contrib, r0);                                  \
            r1 = fmaf(s1, contrib, r1);                                  \
            r2 = fmaf(s2, contrib, r2);                                  \
        }                                                                \
    }

    COORDS(0, inA, adA, fzA, fyA, fxA);
    PREF(inA, adA, a00, a01, a10, a11);

    for (int j = 0; ; ) {
        // prefetch j+1 while consuming j
        COORDS(j + 1, inB, adB, fzB, fyB, fxB);
        PREF(inB, adB, b00, b01, b10, b11);
        CONSUME(j, inA, fzA, fyA, fxA, a00, a01, a10, a11);
        ++j;
        {
            const float t0 = fmaf((float)(2 * j), kDT, tmin);
            if (j >= 32 || t0 >= tmax || alpha >= 1.0f) break;   // uniform
        }
        COORDS(j + 1, inA, adA, fzA, fyA, fxA);
        PREF(inA, adA, a00, a01, a10, a11);
        CONSUME(j, inB, fzB, fyB, fxB, b00, b01, b10, b11);
        ++j;
        {
            const float t0 = fmaf((float)(2 * j), kDT, tmin);
            if (j >= 32 || t0 >= tmax || alpha >= 1.0f) break;   // uniform
        }
    }

#undef COORDS
#undef PREF
#undef CONSUME

    // full-wave rgb reduce (both parity halves contributed)
    r0 = half_sum32(r0); r0 += __shfl_xor(r0, 32);
    r1 = half_sum32(r1); r1 += __shfl_xor(r1, 32);
    r2 = half_sum32(r2); r2 += __shfl_xor(r2, 32);

    if (lane == 0) {
        out[0 * R + ray] = r0;
        out[1 * R + ray] = r1;
        out[2 * R + ray] = r2;
        out[3 * R + ray] = alpha;
        out[4 * R + ray] = r0;
        out[5 * R + ray] = r1;
        out[6 * R + ray] = r2;
        out[7 * R + ray] = alpha;
    }
}

// ---- fallback (r6-style, original f32 template) for tiny ws ----
__global__ __launch_bounds__(256) void raymarch_fb(
    const float* __restrict__ raypos, const float* __restrict__ raydir,
    const float* __restrict__ tminmax, const float* __restrict__ primpos,
    const float* __restrict__ primrot, const float* __restrict__ primscale,
    const float* __restrict__ tmpl, float* __restrict__ out, int R)
{
    const int lane = threadIdx.x & 63;
    const int wid  = threadIdx.x >> 6;
    const int k    = lane & 31;
    const int half = lane >> 5;
    const int ray  = blockIdx.x * 8 + wid * 2 + half;

    const float rpx = raypos[ray*3+0], rpy = raypos[ray*3+1], rpz = raypos[ray*3+2];
    const float rdx = raydir[ray*3+0], rdy = raydir[ray*3+1], rdz = raydir[ray*3+2];
    const float tmin = tminmax[ray*2+0], tmax = tminmax[ray*2+1];

    float A0,A1,A2,D0,D1,D2;
    {
        const float ox = rpx - primpos[k*3+0], oy = rpy - primpos[k*3+1], oz = rpz - primpos[k*3+2];
        const float s0 = primscale[k*3+0], s1 = primscale[k*3+1], s2 = primscale[k*3+2];
        const float* rk = primrot + k*9;
        A0 = (rk[0]*ox+rk[1]*oy+rk[2]*oz)*s0; D0 = (rk[0]*rdx+rk[1]*rdy+rk[2]*rdz)*s0;
        A1 = (rk[3]*ox+rk[4]*oy+rk[5]*oz)*s1; D1 = (rk[3]*rdx+rk[4]*rdy+rk[5]*rdz)*s1;
        A2 = (rk[6]*ox+rk[7]*oy+rk[8]*oz)*s2; D2 = (rk[6]*rdx+rk[7]*rdy+rk[8]*rdz)*s2;
    }
    float alpha = 0.f, r0 = 0.f, r1 = 0.f, r2 = 0.f;
    for (int i = 0; i < 64; ++i) {
        const float t = fmaf((float)i, kDT, tmin);
        const bool live = (t < tmax) && (alpha < 1.0f);
        if (__ballot(live) == 0ull) break;
        const float y0 = fmaf(D0,t,A0), y1 = fmaf(D1,t,A1), y2 = fmaf(D2,t,A2);
        const bool inside = live && fabsf(y0)<=1.f && fabsf(y1)<=1.f && fabsf(y2)<=1.f;
        if (__ballot(inside) == 0ull) continue;
        float s0=0.f,s1=0.f,s2=0.f,s3=0.f;
        if (inside) {
            const float gz=(y0+1.f)*7.5f, gy=(y1+1.f)*7.5f, gx=(y2+1.f)*7.5f;
            const int iz=(int)fminf(floorf(gz),14.f), iy=(int)fminf(floorf(gy),14.f), ix=(int)fminf(floorf(gx),14.f);
            const float fz=fminf(gz-(float)iz,1.f), fy=fminf(gy-(float)iy,1.f), fx=fminf(gx-(float)ix,1.f);
            const float oz_=1.f-fz, oy_=1.f-fy, ox_=1.f-fx;
            const float w000=oz_*oy_*ox_, w001=oz_*oy_*fx, w010=oz_*fy*ox_, w011=oz_*fy*fx;
            const float w100=fz*oy_*ox_, w101=fz*oy_*fx, w110=fz*fy*ox_, w111=fz*fy*fx;
            const float* tp = tmpl + k*16384 + iz*256 + iy*16 + ix;
            float acc[4];
            #pragma unroll
            for (int c = 0; c < 4; ++c) {
                const float* tc = tp + c*4096;
                acc[c] = w000*tc[0]+w001*tc[1]+w010*tc[16]+w011*tc[17]
                       + w100*tc[256]+w101*tc[257]+w110*tc[272]+w111*tc[273];
            }
            s0=acc[0]; s1=acc[1]; s2=acc[2]; s3=acc[3];
        }
        float tot3 = s3;
        #pragma unroll
        for (int m = 1; m < 32; m <<= 1) tot3 += __shfl_xor(tot3, m);
        const float na = fminf(fmaf(tot3, kDT, alpha), 1.0f);
        const float contrib = na - alpha;
        alpha = na;
        r0 = fmaf(s0, contrib, r0); r1 = fmaf(s1, contrib, r1); r2 = fmaf(s2, contrib, r2);
    }
    #pragma unroll
    for (int m = 1; m < 32; m <<= 1) {
        r0 += __shfl_xor(r0, m); r1 += __shfl_xor(r1, m); r2 += __shfl_xor(r2, m);
    }
    if (k == 0) {
        out[0*R+ray]=r0; out[1*R+ray]=r1; out[2*R+ray]=r2; out[3*R+ray]=alpha;
        out[4*R+ray]=r0; out[5*R+ray]=r1; out[6*R+ray]=r2; out[7*R+ray]=alpha;
    }
}

} // namespace

extern "C" void kernel_launch(void* const* d_in, const int* in_sizes, int n_in,
                              void* d_out, int out_size, void* d_ws, size_t ws_size,
                              hipStream_t stream) {
    const float* raypos    = (const float*)d_in[0];
    const float* raydir    = (const float*)d_in[1];
    const float* tminmax   = (const float*)d_in[2];
    const float* primpos   = (const float*)d_in[3];
    const float* primrot   = (const float*)d_in[4];
    const float* primscale = (const float*)d_in[5];
    const float* tmpl      = (const float*)d_in[6];
    float* out = (float*)d_out;

    const int R = in_sizes[0] / 3;   // 16384
    const size_t needH = (size_t)kVox * sizeof(H4);   // 1 MiB

    if (ws_size >= needH) {
        H4* wsH = (H4*)d_ws;
        transpose_tmpl_h<<<dim3(kVox / 256), dim3(256), 0, stream>>>(tmpl, wsH);
        raymarch12<<<dim3(R / 4), dim3(256), 0, stream>>>(
            raypos, raydir, tminmax, primpos, primrot, primscale, wsH, out, R);
    } else {
        raymarch_fb<<<dim3(R / 8), dim3(256), 0, stream>>>(
            raypos, raydir, tminmax, primpos, primrot, primscale, tmpl, out, R);
    }
}

// Round 3
// 86.834 us; speedup vs baseline: 1.5403x; 1.0405x over previous
//
#include <hip/hip_runtime.h>
#include <hip/hip_fp16.h>

// Raymarcher: R=16384 rays, 64 steps, K=32 prims, template (32,4,16,16,16) f32.
// Round 13: r10 layout (lane=(prim,parity), wave-uniform alpha-saturation
// break) but FOUR substeps per loop iteration: each lane evals its prim at
// substeps 4j+parity and 4j+2+parity. Halves per-substep loop overhead
// (ballot/branch/alpha bookkeeping) and doubles per-wave ILP (two independent
// load->lerp chains). Exact 4-term alpha min-prefix chain — identical
// fminf(fmaf(...)) sequence to the serial r10 chain. No speculative
// cross-iteration prefetch (r12's regression). DPP butterfly reduce kept.
// fp16 channel-last template + factorized lerp + 16B x-pair loads from r9/r10.

namespace {

constexpr float kDT  = 1.0f / 64.0f;
constexpr int   kVox = 32 * 4096;   // (k,z,y,x) voxel count

struct H4 { __half2 lo, hi; };                                   // one voxel, 8 B
struct __attribute__((aligned(8))) H4x2 { __half2 l0, h0, l1, h1; }; // voxels (x, x+1), 16 B

// ---- pre-pass: (k,c,z,y,x) f32 -> (k,z,y,x,c) fp16 ----
__global__ __launch_bounds__(256) void transpose_tmpl_h(
    const float* __restrict__ tmpl, H4* __restrict__ wsH)
{
    const int idx = blockIdx.x * 256 + threadIdx.x;     // < 131072
    const int k   = idx >> 12;
    const int rem = idx & 4095;
    const float* src = tmpl + k * 16384 + rem;
    H4 v;
    v.lo = __floats2half2_rn(src[0],    src[4096]);
    v.hi = __floats2half2_rn(src[8192], src[12288]);
    wsH[idx] = v;
}

__device__ __forceinline__ __half2 lerp2(__half2 a, __half2 b, __half2 f) {
    return __hfma2(f, __hsub2(b, a), a);
}

template<int CTRL>
__device__ __forceinline__ float dpp_add(float v) {
    return v + __int_as_float(__builtin_amdgcn_update_dpp(
        0, __float_as_int(v), CTRL, 0xF, 0xF, true));
}

// Sum across each 32-lane half; result in every lane of that half.
__device__ __forceinline__ float half_sum32(float v) {
    v = dpp_add<0xB1>(v);    // quad_perm {1,0,3,2}  == lane^1
    v = dpp_add<0x4E>(v);    // quad_perm {2,3,0,1}  == lane^2
    v = dpp_add<0x141>(v);   // row_half_mirror      == lane^4 (groups uniform)
    v = dpp_add<0x140>(v);   // row_mirror           == lane^8 (groups uniform)
    v += __int_as_float(__builtin_amdgcn_ds_swizzle(__float_as_int(v), 0x401F)); // ^16
    return v;
}

__global__ __launch_bounds__(256) void raymarch13(
    const float* __restrict__ raypos,
    const float* __restrict__ raydir,
    const float* __restrict__ tminmax,
    const float* __restrict__ primpos,
    const float* __restrict__ primrot,
    const float* __restrict__ primscale,
    const H4* __restrict__ wsH,
    float* __restrict__ out,
    int R)
{
    const int lane   = threadIdx.x & 63;
    const int wid    = threadIdx.x >> 6;        // wave 0..3
    const int k      = lane & 31;               // prim owned by this lane
    const int parity = lane >> 5;               // substep parity (0 even, 1 odd)
    const int ray    = blockIdx.x * 4 + wid;    // one ray per wave

    const float rpx = raypos[ray * 3 + 0];
    const float rpy = raypos[ray * 3 + 1];
    const float rpz = raypos[ray * 3 + 2];
    const float rdx = raydir[ray * 3 + 0];
    const float rdy = raydir[ray * 3 + 1];
    const float rdz = raydir[ray * 3 + 2];
    const float tmin = tminmax[ray * 2 + 0];
    const float tmax = tminmax[ray * 2 + 1];

    // Fold prim k into affine y_i(t) = A_i + D_i*t (verified r1-r12 math).
    float A0, A1, A2, D0, D1, D2;
    {
        const float ox = rpx - primpos[k * 3 + 0];
        const float oy = rpy - primpos[k * 3 + 1];
        const float oz = rpz - primpos[k * 3 + 2];
        const float s0 = primscale[k * 3 + 0];
        const float s1 = primscale[k * 3 + 1];
        const float s2 = primscale[k * 3 + 2];
        const float* rk = primrot + k * 9;
        A0 = (rk[0] * ox + rk[1] * oy + rk[2] * oz) * s0;
        D0 = (rk[0] * rdx + rk[1] * rdy + rk[2] * rdz) * s0;
        A1 = (rk[3] * ox + rk[4] * oy + rk[5] * oz) * s1;
        D1 = (rk[3] * rdx + rk[4] * rdy + rk[5] * rdz) * s1;
        A2 = (rk[6] * ox + rk[7] * oy + rk[8] * oz) * s2;
        D2 = (rk[6] * rdx + rk[7] * rdy + rk[8] * rdz) * s2;
    }

    const H4* __restrict__ tbase = wsH + k * 4096;

    float alpha = 0.f;                      // wave-uniform
    float r0 = 0.f, r1 = 0.f, r2 = 0.f;     // per-lane rgb partials

    // Per-lane coords for a given substep index (exact r10 arithmetic).
#define COORDS(SUB, IN, AD, FZ, FY, FX)                                  \
    {                                                                    \
        const float tl = fmaf((float)(SUB), kDT, tmin);                  \
        const float y0 = fmaf(D0, tl, A0);                               \
        const float y1 = fmaf(D1, tl, A1);                               \
        const float y2 = fmaf(D2, tl, A2);                               \
        IN = (tl < tmax) && fabsf(y0) <= 1.0f                            \
           && fabsf(y1) <= 1.0f && fabsf(y2) <= 1.0f;                    \
        const float gz = fmaf(y0, 7.5f, 7.5f);                           \
        const float gy = fmaf(y1, 7.5f, 7.5f);                           \
        const float gx = fmaf(y2, 7.5f, 7.5f);                           \
        const int iz = min((int)gz, 14);                                 \
        const int iy = min((int)gy, 14);                                 \
        const int ix = min((int)gx, 14);                                 \
        FZ = fminf(gz - (float)iz, 1.0f);                                \
        FY = fminf(gy - (float)iy, 1.0f);                                \
        FX = fminf(gx - (float)ix, 1.0f);                                \
        AD = iz * 256 + iy * 16 + ix;                                    \
    }

    // Trilinear eval (corner loads + factorized fp16 lerp) -> s0..s3.
#define EVAL(IN, AD, FZ, FY, FX, S0, S1, S2, S3)                         \
    {                                                                    \
        S0 = 0.f; S1 = 0.f; S2 = 0.f; S3 = 0.f;                         \
        if (IN) {                                                        \
            const H4* tp = tbase + (AD);                                 \
            const H4x2 p00 = *(const H4x2*)(tp + 0);                     \
            const H4x2 p01 = *(const H4x2*)(tp + 16);                    \
            const H4x2 p10 = *(const H4x2*)(tp + 256);                   \
            const H4x2 p11 = *(const H4x2*)(tp + 272);                   \
            const __half2 hz = __float2half2_rn(FZ);                     \
            const __half2 hy = __float2half2_rn(FY);                     \
            const __half2 hx = __float2half2_rn(FX);                     \
            const __half2 q0l0 = lerp2(p00.l0, p10.l0, hz);              \
            const __half2 q0h0 = lerp2(p00.h0, p10.h0, hz);              \
            const __half2 q0l1 = lerp2(p00.l1, p10.l1, hz);              \
            const __half2 q0h1 = lerp2(p00.h1, p10.h1, hz);              \
            const __half2 q1l0 = lerp2(p01.l0, p11.l0, hz);              \
            const __half2 q1h0 = lerp2(p01.h0, p11.h0, hz);              \
            const __half2 q1l1 = lerp2(p01.l1, p11.l1, hz);              \
            const __half2 q1h1 = lerp2(p01.h1, p11.h1, hz);              \
            const __half2 ul0 = lerp2(q0l0, q1l0, hy);                   \
            const __half2 uh0 = lerp2(q0h0, q1h0, hy);                   \
            const __half2 ul1 = lerp2(q0l1, q1l1, hy);                   \
            const __half2 uh1 = lerp2(q0h1, q1h1, hy);                   \
            const __half2 vl = lerp2(ul0, ul1, hx);                      \
            const __half2 vh = lerp2(uh0, uh1, hx);                      \
            const float2 fLo = __half22float2(vl);                       \
            const float2 fHi = __half22float2(vh);                       \
            S0 = fLo.x; S1 = fLo.y; S2 = fHi.x; S3 = fHi.y;              \
        }                                                                \
    }

    for (int j = 0; j < 16; ++j) {
        // quad j covers substeps 4j .. 4j+3; this lane evals 4j+parity
        // (slot a) and 4j+2+parity (slot b).
        bool  inA, inB;
        int   adA, adB;
        float fzA, fyA, fxA, fzB, fyB, fxB;
        COORDS(4 * j + parity,     inA, adA, fzA, fyA, fxA);
        COORDS(4 * j + 2 + parity, inB, adB, fzB, fyB, fxB);

        if (__ballot(inA || inB)) {
            float s0a, s1a, s2a, s3a, s0b, s1b, s2b, s3b;
            EVAL(inA, adA, fzA, fyA, fxA, s0a, s1a, s2a, s3a);
            EVAL(inB, adB, fzB, fyB, fxB, s0b, s1b, s2b, s3b);

            // per-substep density totals: half-reduce + cross-half exchange
            float ta = half_sum32(s3a);           // even half: 4j, odd: 4j+1
            float tb = half_sum32(s3b);           // even half: 4j+2, odd: 4j+3
            const float oa = __shfl_xor(ta, 32);
            const float ob = __shfl_xor(tb, 32);
            const float te0 = parity ? oa : ta;
            const float to0 = parity ? ta : oa;
            const float te1 = parity ? ob : tb;
            const float to1 = parity ? tb : ob;

            // exact 4-substep alpha chain (totals >= 0 => clip == min);
            // identical op sequence to r10's serial per-substep chain.
            const float a1 = fminf(fmaf(te0, kDT, alpha), 1.0f);
            const float c0 = a1 - alpha;
            const float a2 = fminf(fmaf(to0, kDT, a1), 1.0f);
            const float c1 = a2 - a1;
            const float a3 = fminf(fmaf(te1, kDT, a2), 1.0f);
            const float c2 = a3 - a2;
            const float a4 = fminf(fmaf(to1, kDT, a3), 1.0f);
            const float c3 = a4 - a3;
            alpha = a4;

            const float ca = parity ? c1 : c0;    // contrib for slot a
            const float cb = parity ? c3 : c2;    // contrib for slot b
            r0 = fmaf(s0a, ca, fmaf(s0b, cb, r0));
            r1 = fmaf(s1a, ca, fmaf(s1b, cb, r1));
            r2 = fmaf(s2a, ca, fmaf(s2b, cb, r2));
        }

        const float tn = fmaf((float)(4 * j + 4), kDT, tmin);
        if (tn >= tmax || alpha >= 1.0f) break;   // wave-uniform
    }

#undef COORDS
#undef EVAL

    // full-wave rgb reduce (both parity halves contributed)
    r0 = half_sum32(r0); r0 += __shfl_xor(r0, 32);
    r1 = half_sum32(r1); r1 += __shfl_xor(r1, 32);
    r2 = half_sum32(r2); r2 += __shfl_xor(r2, 32);

    if (lane == 0) {
        out[0 * R + ray] = r0;
        out[1 * R + ray] = r1;
        out[2 * R + ray] = r2;
        out[3 * R + ray] = alpha;
        out[4 * R + ray] = r0;
        out[5 * R + ray] = r1;
        out[6 * R + ray] = r2;
        out[7 * R + ray] = alpha;
    }
}

// ---- fallback (r6-style, original f32 template) for tiny ws ----
__global__ __launch_bounds__(256) void raymarch_fb(
    const float* __restrict__ raypos, const float* __restrict__ raydir,
    const float* __restrict__ tminmax, const float* __restrict__ primpos,
    const float* __restrict__ primrot, const float* __restrict__ primscale,
    const float* __restrict__ tmpl, float* __restrict__ out, int R)
{
    const int lane = threadIdx.x & 63;
    const int wid  = threadIdx.x >> 6;
    const int k    = lane & 31;
    const int half = lane >> 5;
    const int ray  = blockIdx.x * 8 + wid * 2 + half;

    const float rpx = raypos[ray*3+0], rpy = raypos[ray*3+1], rpz = raypos[ray*3+2];
    const float rdx = raydir[ray*3+0], rdy = raydir[ray*3+1], rdz = raydir[ray*3+2];
    const float tmin = tminmax[ray*2+0], tmax = tminmax[ray*2+1];

    float A0,A1,A2,D0,D1,D2;
    {
        const float ox = rpx - primpos[k*3+0], oy = rpy - primpos[k*3+1], oz = rpz - primpos[k*3+2];
        const float s0 = primscale[k*3+0], s1 = primscale[k*3+1], s2 = primscale[k*3+2];
        const float* rk = primrot + k*9;
        A0 = (rk[0]*ox+rk[1]*oy+rk[2]*oz)*s0; D0 = (rk[0]*rdx+rk[1]*rdy+rk[2]*rdz)*s0;
        A1 = (rk[3]*ox+rk[4]*oy+rk[5]*oz)*s1; D1 = (rk[3]*rdx+rk[4]*rdy+rk[5]*rdz)*s1;
        A2 = (rk[6]*ox+rk[7]*oy+rk[8]*oz)*s2; D2 = (rk[6]*rdx+rk[7]*rdy+rk[8]*rdz)*s2;
    }
    float alpha = 0.f, r0 = 0.f, r1 = 0.f, r2 = 0.f;
    for (int i = 0; i < 64; ++i) {
        const float t = fmaf((float)i, kDT, tmin);
        const bool live = (t < tmax) && (alpha < 1.0f);
        if (__ballot(live) == 0ull) break;
        const float y0 = fmaf(D0,t,A0), y1 = fmaf(D1,t,A1), y2 = fmaf(D2,t,A2);
        const bool inside = live && fabsf(y0)<=1.f && fabsf(y1)<=1.f && fabsf(y2)<=1.f;
        if (__ballot(inside) == 0ull) continue;
        float s0=0.f,s1=0.f,s2=0.f,s3=0.f;
        if (inside) {
            const float gz=(y0+1.f)*7.5f, gy=(y1+1.f)*7.5f, gx=(y2+1.f)*7.5f;
            const int iz=(int)fminf(floorf(gz),14.f), iy=(int)fminf(floorf(gy),14.f), ix=(int)fminf(floorf(gx),14.f);
            const float fz=fminf(gz-(float)iz,1.f), fy=fminf(gy-(float)iy,1.f), fx=fminf(gx-(float)ix,1.f);
            const float oz_=1.f-fz, oy_=1.f-fy, ox_=1.f-fx;
            const float w000=oz_*oy_*ox_, w001=oz_*oy_*fx, w010=oz_*fy*ox_, w011=oz_*fy*fx;
            const float w100=fz*oy_*ox_, w101=fz*oy_*fx, w110=fz*fy*ox_, w111=fz*fy*fx;
            const float* tp = tmpl + k*16384 + iz*256 + iy*16 + ix;
            float acc[4];
            #pragma unroll
            for (int c = 0; c < 4; ++c) {
                const float* tc = tp + c*4096;
                acc[c] = w000*tc[0]+w001*tc[1]+w010*tc[16]+w011*tc[17]
                       + w100*tc[256]+w101*tc[257]+w110*tc[272]+w111*tc[273];
            }
            s0=acc[0]; s1=acc[1]; s2=acc[2]; s3=acc[3];
        }
        float tot3 = s3;
        #pragma unroll
        for (int m = 1; m < 32; m <<= 1) tot3 += __shfl_xor(tot3, m);
        const float na = fminf(fmaf(tot3, kDT, alpha), 1.0f);
        const float contrib = na - alpha;
        alpha = na;
        r0 = fmaf(s0, contrib, r0); r1 = fmaf(s1, contrib, r1); r2 = fmaf(s2, contrib, r2);
    }
    #pragma unroll
    for (int m = 1; m < 32; m <<= 1) {
        r0 += __shfl_xor(r0, m); r1 += __shfl_xor(r1, m); r2 += __shfl_xor(r2, m);
    }
    if (k == 0) {
        out[0*R+ray]=r0; out[1*R+ray]=r1; out[2*R+ray]=r2; out[3*R+ray]=alpha;
        out[4*R+ray]=r0; out[5*R+ray]=r1; out[6*R+ray]=r2; out[7*R+ray]=alpha;
    }
}

} // namespace

extern "C" void kernel_launch(void* const* d_in, const int* in_sizes, int n_in,
                              void* d_out, int out_size, void* d_ws, size_t ws_size,
                              hipStream_t stream) {
    const float* raypos    = (const float*)d_in[0];
    const float* raydir    = (const float*)d_in[1];
    const float* tminmax   = (const float*)d_in[2];
    const float* primpos   = (const float*)d_in[3];
    const float* primrot   = (const float*)d_in[4];
    const float* primscale = (const float*)d_in[5];
    const float* tmpl      = (const float*)d_in[6];
    float* out = (float*)d_out;

    const int R = in_sizes[0] / 3;   // 16384
    const size_t needH = (size_t)kVox * sizeof(H4);   // 1 MiB

    if (ws_size >= needH) {
        H4* wsH = (H4*)d_ws;
        transpose_tmpl_h<<<dim3(kVox / 256), dim3(256), 0, stream>>>(tmpl, wsH);
        raymarch13<<<dim3(R / 4), dim3(256), 0, stream>>>(
            raypos, raydir, tminmax, primpos, primrot, primscale, wsH, out, R);
    } else {
        raymarch_fb<<<dim3(R / 8), dim3(256), 0, stream>>>(
            raypos, raydir, tminmax, primpos, primrot, primscale, tmpl, out, R);
    }
}

// Round 4
// 86.260 us; speedup vs baseline: 1.5506x; 1.0067x over previous
//
#include <hip/hip_runtime.h>
#include <hip/hip_fp16.h>

// Raymarcher: R=16384 rays, 64 steps, K=32 prims, template (32,4,16,16,16) f32.
// Round 14: r13 structure (lane=(prim,parity), 4 substeps/iter, wave-uniform
// break) + fast-path alpha: pre-saturation the clip() is the identity, so
// per-lane contribs are half-local (ta*DT, tb*DT) and only the alpha update
// needs one cross-half exchange. The exact 4-term min-chain runs only on the
// (at most one) saturating iteration. Removes ~12 inst and ~100+ cy of serial
// cross-lane latency per iteration. Block=128 for finer wave backfill.
// fp16 channel-last template + factorized lerp + 16B x-pair loads from r9-r13.

namespace {

constexpr float kDT  = 1.0f / 64.0f;
constexpr int   kVox = 32 * 4096;   // (k,z,y,x) voxel count

struct H4 { __half2 lo, hi; };                                   // one voxel, 8 B
struct __attribute__((aligned(8))) H4x2 { __half2 l0, h0, l1, h1; }; // voxels (x, x+1), 16 B

// ---- pre-pass: (k,c,z,y,x) f32 -> (k,z,y,x,c) fp16 ----
__global__ __launch_bounds__(256) void transpose_tmpl_h(
    const float* __restrict__ tmpl, H4* __restrict__ wsH)
{
    const int idx = blockIdx.x * 256 + threadIdx.x;     // < 131072
    const int k   = idx >> 12;
    const int rem = idx & 4095;
    const float* src = tmpl + k * 16384 + rem;
    H4 v;
    v.lo = __floats2half2_rn(src[0],    src[4096]);
    v.hi = __floats2half2_rn(src[8192], src[12288]);
    wsH[idx] = v;
}

__device__ __forceinline__ __half2 lerp2(__half2 a, __half2 b, __half2 f) {
    return __hfma2(f, __hsub2(b, a), a);
}

template<int CTRL>
__device__ __forceinline__ float dpp_add(float v) {
    return v + __int_as_float(__builtin_amdgcn_update_dpp(
        0, __float_as_int(v), CTRL, 0xF, 0xF, true));
}

// Sum across each 32-lane half; result in every lane of that half.
__device__ __forceinline__ float half_sum32(float v) {
    v = dpp_add<0xB1>(v);    // quad_perm {1,0,3,2}  == lane^1
    v = dpp_add<0x4E>(v);    // quad_perm {2,3,0,1}  == lane^2
    v = dpp_add<0x141>(v);   // row_half_mirror      == lane^4 (groups uniform)
    v = dpp_add<0x140>(v);   // row_mirror           == lane^8 (groups uniform)
    v += __int_as_float(__builtin_amdgcn_ds_swizzle(__float_as_int(v), 0x401F)); // ^16
    return v;
}

__global__ __launch_bounds__(128) void raymarch14(
    const float* __restrict__ raypos,
    const float* __restrict__ raydir,
    const float* __restrict__ tminmax,
    const float* __restrict__ primpos,
    const float* __restrict__ primrot,
    const float* __restrict__ primscale,
    const H4* __restrict__ wsH,
    float* __restrict__ out,
    int R)
{
    const int lane   = threadIdx.x & 63;
    const int wid    = threadIdx.x >> 6;        // wave 0..1
    const int k      = lane & 31;               // prim owned by this lane
    const int parity = lane >> 5;               // substep parity (0 even, 1 odd)
    const int ray    = blockIdx.x * 2 + wid;    // one ray per wave

    const float rpx = raypos[ray * 3 + 0];
    const float rpy = raypos[ray * 3 + 1];
    const float rpz = raypos[ray * 3 + 2];
    const float rdx = raydir[ray * 3 + 0];
    const float rdy = raydir[ray * 3 + 1];
    const float rdz = raydir[ray * 3 + 2];
    const float tmin = tminmax[ray * 2 + 0];
    const float tmax = tminmax[ray * 2 + 1];

    // Fold prim k into affine y_i(t) = A_i + D_i*t (verified r1-r13 math).
    float A0, A1, A2, D0, D1, D2;
    {
        const float ox = rpx - primpos[k * 3 + 0];
        const float oy = rpy - primpos[k * 3 + 1];
        const float oz = rpz - primpos[k * 3 + 2];
        const float s0 = primscale[k * 3 + 0];
        const float s1 = primscale[k * 3 + 1];
        const float s2 = primscale[k * 3 + 2];
        const float* rk = primrot + k * 9;
        A0 = (rk[0] * ox + rk[1] * oy + rk[2] * oz) * s0;
        D0 = (rk[0] * rdx + rk[1] * rdy + rk[2] * rdz) * s0;
        A1 = (rk[3] * ox + rk[4] * oy + rk[5] * oz) * s1;
        D1 = (rk[3] * rdx + rk[4] * rdy + rk[5] * rdz) * s1;
        A2 = (rk[6] * ox + rk[7] * oy + rk[8] * oz) * s2;
        D2 = (rk[6] * rdx + rk[7] * rdy + rk[8] * rdz) * s2;
    }

    const H4* __restrict__ tbase = wsH + k * 4096;

    float alpha = 0.f;                      // wave-uniform
    float r0 = 0.f, r1 = 0.f, r2 = 0.f;     // per-lane rgb partials

    // Per-lane coords for a given substep index (exact r10 arithmetic).
#define COORDS(SUB, IN, AD, FZ, FY, FX)                                  \
    {                                                                    \
        const float tl = fmaf((float)(SUB), kDT, tmin);                  \
        const float y0 = fmaf(D0, tl, A0);                               \
        const float y1 = fmaf(D1, tl, A1);                               \
        const float y2 = fmaf(D2, tl, A2);                               \
        IN = (tl < tmax) && fabsf(y0) <= 1.0f                            \
           && fabsf(y1) <= 1.0f && fabsf(y2) <= 1.0f;                    \
        const float gz = fmaf(y0, 7.5f, 7.5f);                           \
        const float gy = fmaf(y1, 7.5f, 7.5f);                           \
        const float gx = fmaf(y2, 7.5f, 7.5f);                           \
        const int iz = min((int)gz, 14);                                 \
        const int iy = min((int)gy, 14);                                 \
        const int ix = min((int)gx, 14);                                 \
        FZ = fminf(gz - (float)iz, 1.0f);                                \
        FY = fminf(gy - (float)iy, 1.0f);                                \
        FX = fminf(gx - (float)ix, 1.0f);                                \
        AD = iz * 256 + iy * 16 + ix;                                    \
    }

    // Trilinear eval (corner loads + factorized fp16 lerp) -> s0..s3.
#define EVAL(IN, AD, FZ, FY, FX, S0, S1, S2, S3)                         \
    {                                                                    \
        S0 = 0.f; S1 = 0.f; S2 = 0.f; S3 = 0.f;                         \
        if (IN) {                                                        \
            const H4* tp = tbase + (AD);                                 \
            const H4x2 p00 = *(const H4x2*)(tp + 0);                     \
            const H4x2 p01 = *(const H4x2*)(tp + 16);                    \
            const H4x2 p10 = *(const H4x2*)(tp + 256);                   \
            const H4x2 p11 = *(const H4x2*)(tp + 272);                   \
            const __half2 hz = __float2half2_rn(FZ);                     \
            const __half2 hy = __float2half2_rn(FY);                     \
            const __half2 hx = __float2half2_rn(FX);                     \
            const __half2 q0l0 = lerp2(p00.l0, p10.l0, hz);              \
            const __half2 q0h0 = lerp2(p00.h0, p10.h0, hz);              \
            const __half2 q0l1 = lerp2(p00.l1, p10.l1, hz);              \
            const __half2 q0h1 = lerp2(p00.h1, p10.h1, hz);              \
            const __half2 q1l0 = lerp2(p01.l0, p11.l0, hz);              \
            const __half2 q1h0 = lerp2(p01.h0, p11.h0, hz);              \
            const __half2 q1l1 = lerp2(p01.l1, p11.l1, hz);              \
            const __half2 q1h1 = lerp2(p01.h1, p11.h1, hz);              \
            const __half2 ul0 = lerp2(q0l0, q1l0, hy);                   \
            const __half2 uh0 = lerp2(q0h0, q1h0, hy);                   \
            const __half2 ul1 = lerp2(q0l1, q1l1, hy);                   \
            const __half2 uh1 = lerp2(q0h1, q1h1, hy);                   \
            const __half2 vl = lerp2(ul0, ul1, hx);                      \
            const __half2 vh = lerp2(uh0, uh1, hx);                      \
            const float2 fLo = __half22float2(vl);                       \
            const float2 fHi = __half22float2(vh);                       \
            S0 = fLo.x; S1 = fLo.y; S2 = fHi.x; S3 = fHi.y;              \
        }                                                                \
    }

    for (int j = 0; j < 16; ++j) {
        // quad j covers substeps 4j .. 4j+3; this lane evals 4j+parity
        // (slot a) and 4j+2+parity (slot b).
        bool  inA, inB;
        int   adA, adB;
        float fzA, fyA, fxA, fzB, fyB, fxB;
        COORDS(4 * j + parity,     inA, adA, fzA, fyA, fxA);
        COORDS(4 * j + 2 + parity, inB, adB, fzB, fyB, fxB);

        if (__ballot(inA || inB)) {
            float s0a, s1a, s2a, s3a, s0b, s1b, s2b, s3b;
            EVAL(inA, adA, fzA, fyA, fxA, s0a, s1a, s2a, s3a);
            EVAL(inB, adB, fzB, fyB, fxB, s0b, s1b, s2b, s3b);

            // half-local substep totals: ta = my half's slot-a total,
            // tb = my half's slot-b total (halves hold different parities).
            const float ta = half_sum32(s3a);
            const float tb = half_sum32(s3b);
            const float sum2 = ta + tb;
            const float tot4 = sum2 + __shfl_xor(sum2, 32);  // all 4 substeps
            const float anew = fmaf(tot4, kDT, alpha);

            float ca, cb;
            if (anew < 1.0f) {
                // fast path: no clamp active anywhere in the 4-substep chain
                // => contrib_i == inc_i exactly (to fp rounding ~1e-7, vs
                // 0.0625 fp16-template absmax budget). Half-local, no
                // cross-half exchange, no min-chain.
                ca = ta * kDT;
                cb = tb * kDT;
                alpha = anew;
            } else {
                // slow path (at most one iteration per ray): exact 4-term
                // min-prefix chain, identical to r13/r10 semantics.
                const float oa = __shfl_xor(ta, 32);
                const float ob = __shfl_xor(tb, 32);
                const float te0 = parity ? oa : ta;
                const float to0 = parity ? ta : oa;
                const float te1 = parity ? ob : tb;
                const float to1 = parity ? tb : ob;
                const float a1 = fminf(fmaf(te0, kDT, alpha), 1.0f);
                const float c0 = a1 - alpha;
                const float a2 = fminf(fmaf(to0, kDT, a1), 1.0f);
                const float c1 = a2 - a1;
                const float a3 = fminf(fmaf(te1, kDT, a2), 1.0f);
                const float c2 = a3 - a2;
                const float a4 = fminf(fmaf(to1, kDT, a3), 1.0f);
                const float c3 = a4 - a3;
                alpha = a4;
                ca = parity ? c1 : c0;
                cb = parity ? c3 : c2;
            }

            r0 = fmaf(s0a, ca, fmaf(s0b, cb, r0));
            r1 = fmaf(s1a, ca, fmaf(s1b, cb, r1));
            r2 = fmaf(s2a, ca, fmaf(s2b, cb, r2));
        }

        const float tn = fmaf((float)(4 * j + 4), kDT, tmin);
        if (tn >= tmax || alpha >= 1.0f) break;   // wave-uniform
    }

#undef COORDS
#undef EVAL

    // full-wave rgb reduce (both parity halves contributed)
    r0 = half_sum32(r0); r0 += __shfl_xor(r0, 32);
    r1 = half_sum32(r1); r1 += __shfl_xor(r1, 32);
    r2 = half_sum32(r2); r2 += __shfl_xor(r2, 32);

    if (lane == 0) {
        out[0 * R + ray] = r0;
        out[1 * R + ray] = r1;
        out[2 * R + ray] = r2;
        out[3 * R + ray] = alpha;
        out[4 * R + ray] = r0;
        out[5 * R + ray] = r1;
        out[6 * R + ray] = r2;
        out[7 * R + ray] = alpha;
    }
}

// ---- fallback (r6-style, original f32 template) for tiny ws ----
__global__ __launch_bounds__(256) void raymarch_fb(
    const float* __restrict__ raypos, const float* __restrict__ raydir,
    const float* __restrict__ tminmax, const float* __restrict__ primpos,
    const float* __restrict__ primrot, const float* __restrict__ primscale,
    const float* __restrict__ tmpl, float* __restrict__ out, int R)
{
    const int lane = threadIdx.x & 63;
    const int wid  = threadIdx.x >> 6;
    const int k    = lane & 31;
    const int half = lane >> 5;
    const int ray  = blockIdx.x * 8 + wid * 2 + half;

    const float rpx = raypos[ray*3+0], rpy = raypos[ray*3+1], rpz = raypos[ray*3+2];
    const float rdx = raydir[ray*3+0], rdy = raydir[ray*3+1], rdz = raydir[ray*3+2];
    const float tmin = tminmax[ray*2+0], tmax = tminmax[ray*2+1];

    float A0,A1,A2,D0,D1,D2;
    {
        const float ox = rpx - primpos[k*3+0], oy = rpy - primpos[k*3+1], oz = rpz - primpos[k*3+2];
        const float s0 = primscale[k*3+0], s1 = primscale[k*3+1], s2 = primscale[k*3+2];
        const float* rk = primrot + k*9;
        A0 = (rk[0]*ox+rk[1]*oy+rk[2]*oz)*s0; D0 = (rk[0]*rdx+rk[1]*rdy+rk[2]*rdz)*s0;
        A1 = (rk[3]*ox+rk[4]*oy+rk[5]*oz)*s1; D1 = (rk[3]*rdx+rk[4]*rdy+rk[5]*rdz)*s1;
        A2 = (rk[6]*ox+rk[7]*oy+rk[8]*oz)*s2; D2 = (rk[6]*rdx+rk[7]*rdy+rk[8]*rdz)*s2;
    }
    float alpha = 0.f, r0 = 0.f, r1 = 0.f, r2 = 0.f;
    for (int i = 0; i < 64; ++i) {
        const float t = fmaf((float)i, kDT, tmin);
        const bool live = (t < tmax) && (alpha < 1.0f);
        if (__ballot(live) == 0ull) break;
        const float y0 = fmaf(D0,t,A0), y1 = fmaf(D1,t,A1), y2 = fmaf(D2,t,A2);
        const bool inside = live && fabsf(y0)<=1.f && fabsf(y1)<=1.f && fabsf(y2)<=1.f;
        if (__ballot(inside) == 0ull) continue;
        float s0=0.f,s1=0.f,s2=0.f,s3=0.f;
        if (inside) {
            const float gz=(y0+1.f)*7.5f, gy=(y1+1.f)*7.5f, gx=(y2+1.f)*7.5f;
            const int iz=(int)fminf(floorf(gz),14.f), iy=(int)fminf(floorf(gy),14.f), ix=(int)fminf(floorf(gx),14.f);
            const float fz=fminf(gz-(float)iz,1.f), fy=fminf(gy-(float)iy,1.f), fx=fminf(gx-(float)ix,1.f);
            const float oz_=1.f-fz, oy_=1.f-fy, ox_=1.f-fx;
            const float w000=oz_*oy_*ox_, w001=oz_*oy_*fx, w010=oz_*fy*ox_, w011=oz_*fy*fx;
            const float w100=fz*oy_*ox_, w101=fz*oy_*fx, w110=fz*fy*ox_, w111=fz*fy*fx;
            const float* tp = tmpl + k*16384 + iz*256 + iy*16 + ix;
            float acc[4];
            #pragma unroll
            for (int c = 0; c < 4; ++c) {
                const float* tc = tp + c*4096;
                acc[c] = w000*tc[0]+w001*tc[1]+w010*tc[16]+w011*tc[17]
                       + w100*tc[256]+w101*tc[257]+w110*tc[272]+w111*tc[273];
            }
            s0=acc[0]; s1=acc[1]; s2=acc[2]; s3=acc[3];
        }
        float tot3 = s3;
        #pragma unroll
        for (int m = 1; m < 32; m <<= 1) tot3 += __shfl_xor(tot3, m);
        const float na = fminf(fmaf(tot3, kDT, alpha), 1.0f);
        const float contrib = na - alpha;
        alpha = na;
        r0 = fmaf(s0, contrib, r0); r1 = fmaf(s1, contrib, r1); r2 = fmaf(s2, contrib, r2);
    }
    #pragma unroll
    for (int m = 1; m < 32; m <<= 1) {
        r0 += __shfl_xor(r0, m); r1 += __shfl_xor(r1, m); r2 += __shfl_xor(r2, m);
    }
    if (k == 0) {
        out[0*R+ray]=r0; out[1*R+ray]=r1; out[2*R+ray]=r2; out[3*R+ray]=alpha;
        out[4*R+ray]=r0; out[5*R+ray]=r1; out[6*R+ray]=r2; out[7*R+ray]=alpha;
    }
}

} // namespace

extern "C" void kernel_launch(void* const* d_in, const int* in_sizes, int n_in,
                              void* d_out, int out_size, void* d_ws, size_t ws_size,
                              hipStream_t stream) {
    const float* raypos    = (const float*)d_in[0];
    const float* raydir    = (const float*)d_in[1];
    const float* tminmax   = (const float*)d_in[2];
    const float* primpos   = (const float*)d_in[3];
    const float* primrot   = (const float*)d_in[4];
    const float* primscale = (const float*)d_in[5];
    const float* tmpl      = (const float*)d_in[6];
    float* out = (float*)d_out;

    const int R = in_sizes[0] / 3;   // 16384
    const size_t needH = (size_t)kVox * sizeof(H4);   // 1 MiB

    if (ws_size >= needH) {
        H4* wsH = (H4*)d_ws;
        transpose_tmpl_h<<<dim3(kVox / 256), dim3(256), 0, stream>>>(tmpl, wsH);
        raymarch14<<<dim3(R / 2), dim3(128), 0, stream>>>(
            raypos, raydir, tminmax, primpos, primrot, primscale, wsH, out, R);
    } else {
        raymarch_fb<<<dim3(R / 8), dim3(256), 0, stream>>>(
            raypos, raydir, tminmax, primpos, primrot, primscale, tmpl, out, R);
    }
}